// Round 2
// baseline (205.422 us; speedup 1.0000x reference)
//
#include <hip/hip_runtime.h>
#include <hip/hip_bf16.h>

#define N_ROWS 8192
#define D_DIM  1024
#define DELTA  0.1f
#define EPSF   1e-8f

#define BM 256
#define BN 256
#define BK 64
#define NT (D_DIM / BK)   // 16 K-tiles

typedef __attribute__((ext_vector_type(8))) short bf16x8;
typedef __attribute__((ext_vector_type(4))) float f32x4;

__device__ inline unsigned short f2bf(float f) {
    __hip_bfloat16 h = __float2bfloat16(f);
    return *reinterpret_cast<unsigned short*>(&h);
}

// One block per row: compute xx, yy, xy; write normalized bf16 rows + pos.
__global__ __launch_bounds__(256) void norm_kernel(
    const float* __restrict__ X, const float* __restrict__ Y,
    unsigned short* __restrict__ Xn, unsigned short* __restrict__ Yn,
    float* __restrict__ pos)
{
    const int row = blockIdx.x;
    const int t = threadIdx.x;            // 256 threads, 4 f32 each = 1024
    const float4 xv = reinterpret_cast<const float4*>(X + (size_t)row * D_DIM)[t];
    const float4 yv = reinterpret_cast<const float4*>(Y + (size_t)row * D_DIM)[t];

    float xx = xv.x*xv.x + xv.y*xv.y + xv.z*xv.z + xv.w*xv.w;
    float yy = yv.x*yv.x + yv.y*yv.y + yv.z*yv.z + yv.w*yv.w;
    float xy = xv.x*yv.x + xv.y*yv.y + xv.z*yv.z + xv.w*yv.w;

    #pragma unroll
    for (int off = 32; off > 0; off >>= 1) {
        xx += __shfl_xor(xx, off);
        yy += __shfl_xor(yy, off);
        xy += __shfl_xor(xy, off);
    }
    __shared__ float red[12];
    const int wid = t >> 6, lane = t & 63;
    if (lane == 0) { red[wid] = xx; red[4 + wid] = yy; red[8 + wid] = xy; }
    __syncthreads();
    xx = red[0] + red[1] + red[2] + red[3];
    yy = red[4] + red[5] + red[6] + red[7];
    xy = red[8] + red[9] + red[10] + red[11];

    const float rnx = 1.0f / fmaxf(sqrtf(xx), EPSF);
    const float rny = 1.0f / fmaxf(sqrtf(yy), EPSF);
    if (t == 0) pos[row] = xy * rnx * rny;

    ushort4 ox, oy;
    ox.x = f2bf(xv.x * rnx); ox.y = f2bf(xv.y * rnx);
    ox.z = f2bf(xv.z * rnx); ox.w = f2bf(xv.w * rnx);
    oy.x = f2bf(yv.x * rny); oy.y = f2bf(yv.y * rny);
    oy.z = f2bf(yv.z * rny); oy.w = f2bf(yv.w * rny);
    reinterpret_cast<ushort4*>(Xn + (size_t)row * D_DIM)[t] = ox;
    reinterpret_cast<ushort4*>(Yn + (size_t)row * D_DIM)[t] = oy;
}

#define GLDS16(gptr, lptr) \
    __builtin_amdgcn_global_load_lds((const __attribute__((address_space(1))) void*)(gptr), \
                                     (__attribute__((address_space(3))) void*)(lptr), 16, 0, 0)

// Swizzled LDS read: logical chunk lc (8 bf16 = 16B) of row -> physical chunk lc^(row&7).
__device__ inline bf16x8 ldf(const unsigned short* base, int row, int lc) {
    const int pc = lc ^ (row & 7);
    return *reinterpret_cast<const bf16x8*>(base + row * BK + pc * 8);
}

// Stage one 256x64 bf16 panel (32KB): 4 calls/thread, 16B each.
// LDS dest is linear (global_load_lds requirement); swizzle is applied on the
// GLOBAL source chunk so that LDS[row][p] = global[row][p ^ (row&7)].
#define STAGE_P(dst, gbase, kk) { \
    _Pragma("unroll") \
    for (int q = 0; q < 4; ++q) { \
        const int j = q * 8 + wid; \
        const unsigned short* g = (gbase) + (size_t)(j * 8 + srow) * D_DIM + (kk) + schunk * 8; \
        GLDS16(g, (dst) + j * 512); \
    } }

#define LOAD_A(g) { _Pragma("unroll") for (int mi = 0; mi < 4; ++mi) { \
    const int r = wm * 128 + ((g) * 4 + mi) * 16 + (lane & 15); \
    afr[mi][0] = ldf(a, r, (lane >> 4)); \
    afr[mi][1] = ldf(a, r, 4 + (lane >> 4)); } }

#define LOAD_B(h) { _Pragma("unroll") for (int nj = 0; nj < 2; ++nj) { \
    const int cc = wn * 64 + ((h) * 2 + nj) * 16 + (lane & 15); \
    bfr[(h)*2+nj][0] = ldf(b, cc, (lane >> 4)); \
    bfr[(h)*2+nj][1] = ldf(b, cc, 4 + (lane >> 4)); } }

#define MFMA_Q(g, h) { _Pragma("unroll") for (int mi = 0; mi < 4; ++mi) { \
    _Pragma("unroll") for (int nj = 0; nj < 2; ++nj) { \
        acc[(g)*4+mi][(h)*2+nj] = __builtin_amdgcn_mfma_f32_16x16x32_bf16(afr[mi][0], bfr[(h)*2+nj][0], acc[(g)*4+mi][(h)*2+nj], 0, 0, 0); \
        acc[(g)*4+mi][(h)*2+nj] = __builtin_amdgcn_mfma_f32_16x16x32_bf16(afr[mi][1], bfr[(h)*2+nj][1], acc[(g)*4+mi][(h)*2+nj], 0, 0, 0); } } }

// S = Xn * Yn^T 256x256 tile, 4-phase pipelined, fused hinge + diag mask + sum.
__global__ __launch_bounds__(512, 1) void gemm_loss_kernel(
    const unsigned short* __restrict__ A,   // Xn [N][D] bf16
    const unsigned short* __restrict__ B,   // Yn [N][D] bf16
    const float* __restrict__ pos,
    float* __restrict__ out)
{
    __shared__ __align__(16) unsigned short sA[2][BM * BK];  // 64 KB
    __shared__ __align__(16) unsigned short sB[2][BN * BK];  // 64 KB
    __shared__ float sPos[BM];
    __shared__ float redW[8];

    // XCD-aware swizzle (1024 blocks, 1024 % 8 == 0 -> bijective)
    const int nwg = gridDim.x;
    const int bid = blockIdx.x;
    const int cpx = nwg >> 3;
    const int swz = (bid & 7) * cpx + (bid >> 3);
    const int row0 = (swz >> 5) * BM;   // 32 tiles per dim
    const int col0 = (swz & 31) * BN;

    const int t = threadIdx.x;
    const int lane = t & 63;
    const int wid = t >> 6;          // 8 waves: 2M x 4N
    const int wm = wid >> 2;         // 0..1 -> rows [wm*128, +128)
    const int wn = wid & 3;          // 0..3 -> cols [wn*64, +64)

    // staging per-lane constants: lane -> LDS (row j*8 + srow, phys chunk lane&7)
    const int srow = lane >> 3;                     // 0..7
    const int schunk = (lane & 7) ^ srow;           // pre-swizzled global chunk
    const unsigned short* Ab = A + (size_t)row0 * D_DIM;
    const unsigned short* Bb = B + (size_t)col0 * D_DIM;

    f32x4 acc[8][4] = {};
    bf16x8 afr[4][2], bfr[4][2];

    // prologue: stage tile 0 into buffer 0; stage pos
    STAGE_P(&sA[0][0], Ab, 0);
    STAGE_P(&sB[0][0], Bb, 0);
    if (t < BM) sPos[t] = pos[row0 + t];

    int c = 0;
    for (int kt = 0; kt < NT; ++kt, c ^= 1) {
        // buffer-swap boundary: drain old stage loads (issued ~3 phases ago),
        // then barrier; fence so no LDS access crosses upward.
        asm volatile("s_waitcnt vmcnt(0)" ::: "memory");
        __builtin_amdgcn_s_barrier();
        asm volatile("" ::: "memory");
        __builtin_amdgcn_sched_barrier(0);

        const unsigned short* a = &sA[c][0];
        const unsigned short* b = &sB[c][0];
        const bool pf = (kt + 1) < NT;
        const int kk = (kt + 1) * BK;

        // phase 0: stage next A panel; read A(m0-3),B(n0-1); MFMA quadrant
        if (pf) STAGE_P(&sA[c ^ 1][0], Ab, kk);
        LOAD_A(0); LOAD_B(0);
        __builtin_amdgcn_s_barrier();
        __builtin_amdgcn_s_setprio(1);
        MFMA_Q(0, 0);
        __builtin_amdgcn_s_setprio(0);
        __builtin_amdgcn_s_barrier();

        // phase 1: stage next B panel; read B(n2-3); MFMA quadrant
        if (pf) STAGE_P(&sB[c ^ 1][0], Bb, kk);
        LOAD_B(1);
        __builtin_amdgcn_s_barrier();
        __builtin_amdgcn_s_setprio(1);
        MFMA_Q(0, 1);
        __builtin_amdgcn_s_setprio(0);
        __builtin_amdgcn_s_barrier();

        // phase 2: read A(m4-7); MFMA quadrant
        LOAD_A(1);
        __builtin_amdgcn_s_barrier();
        __builtin_amdgcn_s_setprio(1);
        MFMA_Q(1, 1);
        __builtin_amdgcn_s_setprio(0);
        __builtin_amdgcn_s_barrier();

        // phase 3: pure MFMA (regs already live)
        __builtin_amdgcn_s_setprio(1);
        MFMA_Q(1, 0);
        __builtin_amdgcn_s_setprio(0);
    }

    // epilogue: hinge = max(0, DELTA - pos[i] + S[i][j]), skip diagonal, sum
    float local = 0.0f;
    #pragma unroll
    for (int mi = 0; mi < 8; ++mi) {
        #pragma unroll
        for (int jj = 0; jj < 4; ++jj) {
            const int lr = wm * 128 + mi * 16 + (lane >> 4) * 4 + jj;
            const int gr = row0 + lr;
            const float basev = DELTA - sPos[lr];
            #pragma unroll
            for (int nj = 0; nj < 4; ++nj) {
                const int gc = col0 + wn * 64 + nj * 16 + (lane & 15);
                float h = basev + acc[mi][nj][jj];
                h = fmaxf(h, 0.0f);
                if (gr == gc) h = 0.0f;
                local += h;
            }
        }
    }
    #pragma unroll
    for (int off = 32; off > 0; off >>= 1) local += __shfl_xor(local, off);
    if (lane == 0) redW[wid] = local;
    __syncthreads();
    if (t == 0) {
        float s = 0.0f;
        #pragma unroll
        for (int w = 0; w < 8; ++w) s += redW[w];
        atomicAdd(out, s);
    }
}

extern "C" void kernel_launch(void* const* d_in, const int* in_sizes, int n_in,
                              void* d_out, int out_size, void* d_ws, size_t ws_size,
                              hipStream_t stream) {
    const float* X = (const float*)d_in[0];
    const float* Y = (const float*)d_in[1];
    float* out = (float*)d_out;

    unsigned short* Xn = (unsigned short*)d_ws;
    unsigned short* Yn = Xn + (size_t)N_ROWS * D_DIM;
    float* pos = (float*)(Yn + (size_t)N_ROWS * D_DIM);

    hipMemsetAsync(d_out, 0, sizeof(float), stream);
    norm_kernel<<<N_ROWS, 256, 0, stream>>>(X, Y, Xn, Yn, pos);
    const int ntiles = (N_ROWS / BM) * (N_ROWS / BN);   // 1024
    gemm_loss_kernel<<<dim3(ntiles), 512, 0, stream>>>(Xn, Yn, pos, out);
}

// Round 3
// 140.939 us; speedup vs baseline: 1.4575x; 1.4575x over previous
//
#include <hip/hip_runtime.h>
#include <hip/hip_bf16.h>

#define N_ROWS 8192
#define D_DIM  1024
#define DELTA  0.1f
#define EPSF   1e-8f

#define BM 256
#define BN 256
#define BK 64
#define NT (D_DIM / BK)   // 16 K-tiles

typedef __attribute__((ext_vector_type(8))) short bf16x8;
typedef __attribute__((ext_vector_type(4))) float f32x4;

__device__ inline unsigned short f2bf(float f) {
    __hip_bfloat16 h = __float2bfloat16(f);
    return *reinterpret_cast<unsigned short*>(&h);
}

// One block per row: compute xx, yy, xy; write normalized bf16 rows + pos.
__global__ __launch_bounds__(256) void norm_kernel(
    const float* __restrict__ X, const float* __restrict__ Y,
    unsigned short* __restrict__ Xn, unsigned short* __restrict__ Yn,
    float* __restrict__ pos)
{
    const int row = blockIdx.x;
    const int t = threadIdx.x;            // 256 threads, 4 f32 each = 1024
    const float4 xv = reinterpret_cast<const float4*>(X + (size_t)row * D_DIM)[t];
    const float4 yv = reinterpret_cast<const float4*>(Y + (size_t)row * D_DIM)[t];

    float xx = xv.x*xv.x + xv.y*xv.y + xv.z*xv.z + xv.w*xv.w;
    float yy = yv.x*yv.x + yv.y*yv.y + yv.z*yv.z + yv.w*yv.w;
    float xy = xv.x*yv.x + xv.y*yv.y + xv.z*yv.z + xv.w*yv.w;

    #pragma unroll
    for (int off = 32; off > 0; off >>= 1) {
        xx += __shfl_xor(xx, off);
        yy += __shfl_xor(yy, off);
        xy += __shfl_xor(xy, off);
    }
    __shared__ float red[12];
    const int wid = t >> 6, lane = t & 63;
    if (lane == 0) { red[wid] = xx; red[4 + wid] = yy; red[8 + wid] = xy; }
    __syncthreads();
    xx = red[0] + red[1] + red[2] + red[3];
    yy = red[4] + red[5] + red[6] + red[7];
    xy = red[8] + red[9] + red[10] + red[11];

    const float rnx = 1.0f / fmaxf(sqrtf(xx), EPSF);
    const float rny = 1.0f / fmaxf(sqrtf(yy), EPSF);
    if (t == 0) pos[row] = xy * rnx * rny;

    ushort4 ox, oy;
    ox.x = f2bf(xv.x * rnx); ox.y = f2bf(xv.y * rnx);
    ox.z = f2bf(xv.z * rnx); ox.w = f2bf(xv.w * rnx);
    oy.x = f2bf(yv.x * rny); oy.y = f2bf(yv.y * rny);
    oy.z = f2bf(yv.z * rny); oy.w = f2bf(yv.w * rny);
    reinterpret_cast<ushort4*>(Xn + (size_t)row * D_DIM)[t] = ox;
    reinterpret_cast<ushort4*>(Yn + (size_t)row * D_DIM)[t] = oy;
}

#define GLDS16(gptr, lptr) \
    __builtin_amdgcn_global_load_lds((const __attribute__((address_space(1))) void*)(gptr), \
                                     (__attribute__((address_space(3))) void*)(lptr), 16, 0, 0)

// Swizzled LDS read: logical chunk lc (8 bf16 = 16B) of row -> physical chunk lc^(row&7).
__device__ inline bf16x8 ldf(const unsigned short* base, int row, int lc) {
    const int pc = lc ^ (row & 7);
    return *reinterpret_cast<const bf16x8*>(base + row * BK + pc * 8);
}

// Stage one 256x64 bf16 panel (32KB): 4 gload_lds/thread, 16B each.
// LDS dest linear (global_load_lds requirement); swizzle applied on the GLOBAL
// source chunk so that LDS[row][p] = global[row][p ^ (row&7)].
#define STAGE_P(dst, gbase, kk) { \
    _Pragma("unroll") \
    for (int q = 0; q < 4; ++q) { \
        const int j = q * 8 + wid; \
        const unsigned short* g = (gbase) + (size_t)(j * 8 + srow) * D_DIM + (kk) + schunk * 8; \
        GLDS16(g, (dst) + j * 512); \
    } }

#define LOAD_A(g) { _Pragma("unroll") for (int mi = 0; mi < 4; ++mi) { \
    const int r = wm * 128 + ((g) * 4 + mi) * 16 + (lane & 15); \
    afr[mi][0] = ldf(a, r, (lane >> 4)); \
    afr[mi][1] = ldf(a, r, 4 + (lane >> 4)); } }

#define LOAD_B_ALL() { _Pragma("unroll") for (int nj = 0; nj < 4; ++nj) { \
    const int cc = wn * 64 + nj * 16 + (lane & 15); \
    bfr[nj][0] = ldf(b, cc, (lane >> 4)); \
    bfr[nj][1] = ldf(b, cc, 4 + (lane >> 4)); } }

#define MFMA_Q(g, h) { _Pragma("unroll") for (int mi = 0; mi < 4; ++mi) { \
    _Pragma("unroll") for (int nj = 0; nj < 2; ++nj) { \
        acc[(g)*4+mi][(h)*2+nj] = __builtin_amdgcn_mfma_f32_16x16x32_bf16(afr[mi][0], bfr[(h)*2+nj][0], acc[(g)*4+mi][(h)*2+nj], 0, 0, 0); \
        acc[(g)*4+mi][(h)*2+nj] = __builtin_amdgcn_mfma_f32_16x16x32_bf16(afr[mi][1], bfr[(h)*2+nj][1], acc[(g)*4+mi][(h)*2+nj], 0, 0, 0); } } }

// S = Xn * Yn^T 256x256 tile; counted-vmcnt pipeline (prefetch distance 2,
// in-place buffer reuse after whole-tile register fetch); fused hinge + sum.
__global__ __launch_bounds__(512, 2) void gemm_loss_kernel(
    const unsigned short* __restrict__ A,   // Xn [N][D] bf16
    const unsigned short* __restrict__ B,   // Yn [N][D] bf16
    const float* __restrict__ pos,
    float* __restrict__ out)
{
    __shared__ __align__(16) unsigned short sA[2][BM * BK];  // 64 KB
    __shared__ __align__(16) unsigned short sB[2][BN * BK];  // 64 KB
    __shared__ float sPos[BM];
    __shared__ float redW[8];

    // XCD-aware swizzle (1024 blocks, 1024 % 8 == 0 -> bijective)
    const int nwg = gridDim.x;
    const int bid = blockIdx.x;
    const int cpx = nwg >> 3;
    const int swz = (bid & 7) * cpx + (bid >> 3);
    const int row0 = (swz >> 5) * BM;   // 32 tiles per dim
    const int col0 = (swz & 31) * BN;

    const int tid = threadIdx.x;
    const int lane = tid & 63;
    const int wid = tid >> 6;        // 8 waves: 2M x 4N
    const int wm = wid >> 2;         // rows [wm*128, +128)
    const int wn = wid & 3;          // cols [wn*64, +64)

    const int srow = lane >> 3;                     // 0..7
    const int schunk = (lane & 7) ^ srow;           // pre-swizzled global chunk
    const unsigned short* Ab = A + (size_t)row0 * D_DIM;
    const unsigned short* Bb = B + (size_t)col0 * D_DIM;

    f32x4 acc[8][4] = {};
    bf16x8 afr[4][2], bfr[4][2];

    // prologue: stage tiles 0 and 1 (16 loads/thread in flight); stage pos
    STAGE_P(&sA[0][0], Ab, 0);
    STAGE_P(&sB[0][0], Bb, 0);
    STAGE_P(&sA[1][0], Ab, BK);
    STAGE_P(&sB[1][0], Bb, BK);
    if (tid < BM) sPos[tid] = pos[row0 + tid];

    for (int kt = 0; kt < NT - 1; ++kt) {
        const int c = kt & 1;
        // counted wait: tile kt's 8 loads (oldest) complete; tile kt+1's stay in flight
        asm volatile("s_waitcnt vmcnt(8)" ::: "memory");
        __builtin_amdgcn_s_barrier();
        __builtin_amdgcn_sched_barrier(0);

        const unsigned short* a = &sA[c][0];
        const unsigned short* b = &sB[c][0];

        LOAD_A(0);
        LOAD_B_ALL();
        __builtin_amdgcn_s_setprio(1);
        MFMA_Q(0, 0); MFMA_Q(0, 1);
        __builtin_amdgcn_s_setprio(0);
        LOAD_A(1);
        // whole buffer consumed by every wave -> safe to restage in place
        asm volatile("s_waitcnt lgkmcnt(0)" ::: "memory");
        __builtin_amdgcn_s_barrier();
        __builtin_amdgcn_sched_barrier(0);
        if (kt + 2 < NT) {
            STAGE_P(&sA[c][0], Ab, (kt + 2) * BK);
            STAGE_P(&sB[c][0], Bb, (kt + 2) * BK);
        }
        __builtin_amdgcn_s_setprio(1);
        MFMA_Q(1, 0); MFMA_Q(1, 1);
        __builtin_amdgcn_s_setprio(0);
    }
    {   // last tile (drain)
        const unsigned short* a = &sA[(NT - 1) & 1][0];
        const unsigned short* b = &sB[(NT - 1) & 1][0];
        asm volatile("s_waitcnt vmcnt(0)" ::: "memory");
        __builtin_amdgcn_s_barrier();
        __builtin_amdgcn_sched_barrier(0);
        LOAD_A(0);
        LOAD_B_ALL();
        __builtin_amdgcn_s_setprio(1);
        MFMA_Q(0, 0); MFMA_Q(0, 1);
        __builtin_amdgcn_s_setprio(0);
        LOAD_A(1);
        __builtin_amdgcn_s_setprio(1);
        MFMA_Q(1, 0); MFMA_Q(1, 1);
        __builtin_amdgcn_s_setprio(0);
    }

    // epilogue: hinge = max(0, DELTA - pos[i] + S[i][j]), skip diagonal, sum
    float local = 0.0f;
    #pragma unroll
    for (int mi = 0; mi < 8; ++mi) {
        #pragma unroll
        for (int jj = 0; jj < 4; ++jj) {
            const int lr = wm * 128 + mi * 16 + (lane >> 4) * 4 + jj;
            const int gr = row0 + lr;
            const float basev = DELTA - sPos[lr];
            #pragma unroll
            for (int nj = 0; nj < 4; ++nj) {
                const int gc = col0 + wn * 64 + nj * 16 + (lane & 15);
                float h = basev + acc[mi][nj][jj];
                h = fmaxf(h, 0.0f);
                if (gr == gc) h = 0.0f;
                local += h;
            }
        }
    }
    #pragma unroll
    for (int off = 32; off > 0; off >>= 1) local += __shfl_xor(local, off);
    if (lane == 0) redW[wid] = local;
    __syncthreads();
    if (tid == 0) {
        float s = 0.0f;
        #pragma unroll
        for (int w = 0; w < 8; ++w) s += redW[w];
        atomicAdd(out, s);
    }
}

extern "C" void kernel_launch(void* const* d_in, const int* in_sizes, int n_in,
                              void* d_out, int out_size, void* d_ws, size_t ws_size,
                              hipStream_t stream) {
    const float* X = (const float*)d_in[0];
    const float* Y = (const float*)d_in[1];
    float* out = (float*)d_out;

    unsigned short* Xn = (unsigned short*)d_ws;
    unsigned short* Yn = Xn + (size_t)N_ROWS * D_DIM;
    float* pos = (float*)(Yn + (size_t)N_ROWS * D_DIM);

    hipMemsetAsync(d_out, 0, sizeof(float), stream);
    norm_kernel<<<N_ROWS, 256, 0, stream>>>(X, Y, Xn, Yn, pos);
    const int ntiles = (N_ROWS / BM) * (N_ROWS / BN);   // 1024
    gemm_loss_kernel<<<dim3(ntiles), 512, 0, stream>>>(Xn, Yn, pos, out);
}